// Round 1
// baseline (373.225 us; speedup 1.0000x reference)
//
#include <hip/hip_runtime.h>
#include <hip/hip_bf16.h>

#define THREADS 256

static constexpr int M_TOT = 8192;   // 4 * 2048
static constexpr int N_TOT = 4096;   // OUT_F
static constexpr int K_TOT = 4096;   // IN_F

typedef __bf16 bf16x8 __attribute__((ext_vector_type(8)));
typedef float f32x4 __attribute__((ext_vector_type(4)));
typedef unsigned short u16x8 __attribute__((ext_vector_type(8)));

__device__ __forceinline__ unsigned short f2bf(float f) {
  return __builtin_bit_cast(unsigned short, (__bf16)f);
}

// FP4 E2M1 decode: mag 0..7 -> 0,0.5,1,1.5,2,3,4,6 ; bit 3 = sign
__device__ __forceinline__ float fp4_decode(int idx) {
  unsigned u = (unsigned)idx & 15u;
  unsigned sgn = (u >> 3) << 31;
  unsigned mag = u & 7u;
  unsigned e = mag >> 1, m = mag & 1u;
  unsigned bits = (e == 0u) ? (m ? 0x3F000000u : 0u)            // 0.5 or 0
                            : (((126u + e) << 23) | (m << 22)); // 1,1.5,2,3,4,6
  return __uint_as_float(bits | sgn);
}

__device__ __forceinline__ void glds16(const void* g, void* l) {
  __builtin_amdgcn_global_load_lds(
      (__attribute__((address_space(1))) void*)g,
      (__attribute__((address_space(3))) void*)l, 16, 0, 0);
}

// ---- prepass: weights int32 idx + scales -> bf16 W [N][K] --------------------
__global__ __launch_bounds__(THREADS) void dequant_w_kernel(
    const int* __restrict__ idx, const float* __restrict__ scales,
    unsigned short* __restrict__ W) {
  const int t = blockIdx.x * THREADS + threadIdx.x;  // 4 indices per thread
  const int4 v = reinterpret_cast<const int4*>(idx)[t];
  const float s = scales[t >> 2];                    // (t*4)/16
  ushort4 o;
  o.x = f2bf(fp4_decode(v.x) * s);
  o.y = f2bf(fp4_decode(v.y) * s);
  o.z = f2bf(fp4_decode(v.z) * s);
  o.w = f2bf(fp4_decode(v.w) * s);
  reinterpret_cast<ushort4*>(W)[t] = o;
}

// ---- prepass: x fp32 -> bf16 A [M][K] ---------------------------------------
__global__ __launch_bounds__(THREADS) void convert_x_kernel(
    const float* __restrict__ x, unsigned short* __restrict__ A) {
  const int t = blockIdx.x * THREADS + threadIdx.x;  // 8 floats per thread
  const float4* xp = reinterpret_cast<const float4*>(x);
  const float4 a = xp[2 * t], b = xp[2 * t + 1];
  u16x8 o;
  o[0] = f2bf(a.x); o[1] = f2bf(a.y); o[2] = f2bf(a.z); o[3] = f2bf(a.w);
  o[4] = f2bf(b.x); o[5] = f2bf(b.y); o[6] = f2bf(b.z); o[7] = f2bf(b.w);
  reinterpret_cast<u16x8*>(A)[t] = o;
}

// ---- GEMM: C = A @ W^T + bias  (128x128 tile, BK=32, 4 waves 2x2) -----------
// MODE 0: A,B bf16 in ws via global_load_lds (fast)
// MODE 1: B bf16 in ws; A reg-staged fp32->bf16
// MODE 2: fully fused (A from x, B dequantized inline)
template <int MODE>
__global__ __launch_bounds__(THREADS) void gemm_kernel(
    const unsigned short* __restrict__ Abf, const unsigned short* __restrict__ Wbf,
    const float* __restrict__ x, const int* __restrict__ widx,
    const float* __restrict__ wsc, const float* __restrict__ bias,
    float* __restrict__ out) {
  __shared__ alignas(16) unsigned short lds_a[128 * 32];
  __shared__ alignas(16) unsigned short lds_b[128 * 32];

  const int t = threadIdx.x;
  const int bm = blockIdx.x & 63;   // 64 M-blocks
  const int bn = blockIdx.x >> 6;   // 32 N-blocks
  const int lane = t & 63;
  const int wid = t >> 6;
  const int wr = wid >> 1, wc = wid & 1;

  f32x4 acc[4][4];
#pragma unroll
  for (int i = 0; i < 4; ++i)
#pragma unroll
    for (int j = 0; j < 4; ++j) acc[i][j] = f32x4{0.f, 0.f, 0.f, 0.f};

  // MODE 0 staging: thread t covers 8 bf16 at tile elem offset t*8 (row t/4, col (t%4)*8)
  const unsigned short* gA0 = Abf + (size_t)(bm * 128 + (t >> 2)) * K_TOT + (t & 3) * 8;
  const unsigned short* gB0 = Wbf + (size_t)(bn * 128 + (t >> 2)) * K_TOT + (t & 3) * 8;

  // reg-staging: thread t covers row t/2, k-half (t&1)*16
  const float* gx = x + (size_t)(bm * 128 + (t >> 1)) * K_TOT + (t & 1) * 16;
  const int* gi = widx + (size_t)(bn * 128 + (t >> 1)) * K_TOT + (t & 1) * 16;
  const float* gs = wsc + (size_t)(bn * 128 + (t >> 1)) * 256 + (t & 1);
  unsigned short* la = &lds_a[(t >> 1) * 32 + (t & 1) * 16];
  unsigned short* lb = &lds_b[(t >> 1) * 32 + (t & 1) * 16];

  const int arow = wr * 64 + (lane & 15);
  const int brow = wc * 64 + (lane & 15);
  const int kc = (lane >> 4) * 8;

  for (int k0 = 0; k0 < K_TOT; k0 += 32) {
    if constexpr (MODE == 0) {
      glds16(gA0 + k0, &lds_a[t * 8]);
      glds16(gA0 + (size_t)64 * K_TOT + k0, &lds_a[2048 + t * 8]);
    } else {
      const float4 f0 = *(const float4*)(gx + k0);
      const float4 f1 = *(const float4*)(gx + k0 + 4);
      const float4 f2 = *(const float4*)(gx + k0 + 8);
      const float4 f3 = *(const float4*)(gx + k0 + 12);
      u16x8 lo, hi;
      lo[0] = f2bf(f0.x); lo[1] = f2bf(f0.y); lo[2] = f2bf(f0.z); lo[3] = f2bf(f0.w);
      lo[4] = f2bf(f1.x); lo[5] = f2bf(f1.y); lo[6] = f2bf(f1.z); lo[7] = f2bf(f1.w);
      hi[0] = f2bf(f2.x); hi[1] = f2bf(f2.y); hi[2] = f2bf(f2.z); hi[3] = f2bf(f2.w);
      hi[4] = f2bf(f3.x); hi[5] = f2bf(f3.y); hi[6] = f2bf(f3.z); hi[7] = f2bf(f3.w);
      *reinterpret_cast<u16x8*>(la) = lo;
      *reinterpret_cast<u16x8*>(la + 8) = hi;
    }
    if constexpr (MODE <= 1) {
      glds16(gB0 + k0, &lds_b[t * 8]);
      glds16(gB0 + (size_t)64 * K_TOT + k0, &lds_b[2048 + t * 8]);
    } else {
      const int4 v0 = *(const int4*)(gi + k0);
      const int4 v1 = *(const int4*)(gi + k0 + 4);
      const int4 v2 = *(const int4*)(gi + k0 + 8);
      const int4 v3 = *(const int4*)(gi + k0 + 12);
      const float s = gs[k0 >> 4];
      u16x8 lo, hi;
      lo[0] = f2bf(fp4_decode(v0.x) * s); lo[1] = f2bf(fp4_decode(v0.y) * s);
      lo[2] = f2bf(fp4_decode(v0.z) * s); lo[3] = f2bf(fp4_decode(v0.w) * s);
      lo[4] = f2bf(fp4_decode(v1.x) * s); lo[5] = f2bf(fp4_decode(v1.y) * s);
      lo[6] = f2bf(fp4_decode(v1.z) * s); lo[7] = f2bf(fp4_decode(v1.w) * s);
      hi[0] = f2bf(fp4_decode(v2.x) * s); hi[1] = f2bf(fp4_decode(v2.y) * s);
      hi[2] = f2bf(fp4_decode(v2.z) * s); hi[3] = f2bf(fp4_decode(v2.w) * s);
      hi[4] = f2bf(fp4_decode(v3.x) * s); hi[5] = f2bf(fp4_decode(v3.y) * s);
      hi[6] = f2bf(fp4_decode(v3.z) * s); hi[7] = f2bf(fp4_decode(v3.w) * s);
      *reinterpret_cast<u16x8*>(lb) = lo;
      *reinterpret_cast<u16x8*>(lb + 8) = hi;
    }
    __syncthreads();  // compiler drains vmcnt/lgkmcnt before barrier

    bf16x8 af[4], bfr[4];
#pragma unroll
    for (int i = 0; i < 4; ++i)
      af[i] = *reinterpret_cast<const bf16x8*>(&lds_a[(arow + i * 16) * 32 + kc]);
#pragma unroll
    for (int j = 0; j < 4; ++j)
      bfr[j] = *reinterpret_cast<const bf16x8*>(&lds_b[(brow + j * 16) * 32 + kc]);
#pragma unroll
    for (int i = 0; i < 4; ++i)
#pragma unroll
      for (int j = 0; j < 4; ++j)
        acc[i][j] = __builtin_amdgcn_mfma_f32_16x16x32_bf16(af[i], bfr[j], acc[i][j], 0, 0, 0);
    __syncthreads();
  }

  // epilogue: C/D layout col = lane&15, row = (lane>>4)*4 + q  [m89/m91]
  const int orow0 = bm * 128 + wr * 64 + ((lane >> 4) << 2);
  const int ocol0 = bn * 128 + wc * 64 + (lane & 15);
  float bj[4];
#pragma unroll
  for (int j = 0; j < 4; ++j) bj[j] = bias[ocol0 + j * 16];
#pragma unroll
  for (int i = 0; i < 4; ++i)
#pragma unroll
    for (int j = 0; j < 4; ++j)
#pragma unroll
      for (int q = 0; q < 4; ++q)
        out[(size_t)(orow0 + i * 16 + q) * N_TOT + ocol0 + j * 16] = acc[i][j][q] + bj[j];
}

extern "C" void kernel_launch(void* const* d_in, const int* in_sizes, int n_in,
                              void* d_out, int out_size, void* d_ws, size_t ws_size,
                              hipStream_t stream) {
  const float* x = (const float*)d_in[0];
  const int* widx = (const int*)d_in[1];
  const float* wsc = (const float*)d_in[2];
  const float* bias = (const float*)d_in[3];
  float* out = (float*)d_out;

  const size_t needA = (size_t)M_TOT * K_TOT * 2;  // 64 MiB bf16 x
  const size_t needB = (size_t)N_TOT * K_TOT * 2;  // 32 MiB bf16 W
  const dim3 blk(THREADS);
  const int gemm_grid = (M_TOT / 128) * (N_TOT / 128);  // 2048

  if (ws_size >= needA + needB) {
    unsigned short* Abf = (unsigned short*)d_ws;
    unsigned short* Wbf = (unsigned short*)((char*)d_ws + needA);
    convert_x_kernel<<<dim3(((size_t)M_TOT * K_TOT / 8) / THREADS), blk, 0, stream>>>(x, Abf);
    dequant_w_kernel<<<dim3(((size_t)N_TOT * K_TOT / 4) / THREADS), blk, 0, stream>>>(widx, wsc, Wbf);
    gemm_kernel<0><<<dim3(gemm_grid), blk, 0, stream>>>(Abf, Wbf, x, widx, wsc, bias, out);
  } else if (ws_size >= needB) {
    unsigned short* Wbf = (unsigned short*)d_ws;
    dequant_w_kernel<<<dim3(((size_t)N_TOT * K_TOT / 4) / THREADS), blk, 0, stream>>>(widx, wsc, Wbf);
    gemm_kernel<1><<<dim3(gemm_grid), blk, 0, stream>>>(nullptr, Wbf, x, widx, wsc, bias, out);
  } else {
    gemm_kernel<2><<<dim3(gemm_grid), blk, 0, stream>>>(nullptr, nullptr, x, widx, wsc, bias, out);
  }
}

// Round 2
// 292.698 us; speedup vs baseline: 1.2751x; 1.2751x over previous
//
#include <hip/hip_runtime.h>
#include <hip/hip_bf16.h>

static constexpr int M_TOT = 8192;   // 4 * 2048
static constexpr int N_TOT = 4096;   // OUT_F
static constexpr int K_TOT = 4096;   // IN_F

static constexpr int BM = 256, BN = 256, BK = 32;
static constexpr int NT = K_TOT / BK;        // 128 K-tiles
static constexpr int GTHREADS = 512;         // 8 waves (2 M x 4 N)
static constexpr int BUF_BYTES = 32768;      // A 16K + B 16K per K-tile buffer
static constexpr int LDS_BYTES = 4 * BUF_BYTES;  // ring-4 = 128 KiB

typedef __bf16 bf16x8 __attribute__((ext_vector_type(8)));
typedef float f32x4 __attribute__((ext_vector_type(4)));
typedef unsigned short u16x8 __attribute__((ext_vector_type(8)));

__device__ __forceinline__ unsigned short f2bf(float f) {
  return __builtin_bit_cast(unsigned short, (__bf16)f);
}

// FP4 E2M1 decode: mag 0..7 -> 0,0.5,1,1.5,2,3,4,6 ; bit 3 = sign
__device__ __forceinline__ float fp4_decode(int idx) {
  unsigned u = (unsigned)idx & 15u;
  unsigned sgn = (u >> 3) << 31;
  unsigned mag = u & 7u;
  unsigned e = mag >> 1, m = mag & 1u;
  unsigned bits = (e == 0u) ? (m ? 0x3F000000u : 0u)
                            : (((126u + e) << 23) | (m << 22));
  return __uint_as_float(bits | sgn);
}

__device__ __forceinline__ void glds16(const void* g, void* l) {
  __builtin_amdgcn_global_load_lds(
      (__attribute__((address_space(1))) void*)g,
      (__attribute__((address_space(3))) void*)l, 16, 0, 0);
}

// ---- prepass: weights int32 idx + scales -> bf16 W [N][K] -------------------
__global__ __launch_bounds__(256) void dequant_w_kernel(
    const int* __restrict__ idx, const float* __restrict__ scales,
    unsigned short* __restrict__ W) {
  const int t = blockIdx.x * 256 + threadIdx.x;  // 4 indices per thread
  const int4 v = reinterpret_cast<const int4*>(idx)[t];
  const float s = scales[t >> 2];
  ushort4 o;
  o.x = f2bf(fp4_decode(v.x) * s);
  o.y = f2bf(fp4_decode(v.y) * s);
  o.z = f2bf(fp4_decode(v.z) * s);
  o.w = f2bf(fp4_decode(v.w) * s);
  reinterpret_cast<ushort4*>(W)[t] = o;
}

// ---- prepass: x fp32 -> bf16 A [M][K] ---------------------------------------
__global__ __launch_bounds__(256) void convert_x_kernel(
    const float* __restrict__ x, unsigned short* __restrict__ A) {
  const int t = blockIdx.x * 256 + threadIdx.x;  // 8 floats per thread
  const float4* xp = reinterpret_cast<const float4*>(x);
  const float4 a = xp[2 * t], b = xp[2 * t + 1];
  u16x8 o;
  o[0] = f2bf(a.x); o[1] = f2bf(a.y); o[2] = f2bf(a.z); o[3] = f2bf(a.w);
  o[4] = f2bf(b.x); o[5] = f2bf(b.y); o[6] = f2bf(b.z); o[7] = f2bf(b.w);
  reinterpret_cast<u16x8*>(A)[t] = o;
}

// ---- GEMM: 256x256 tile, BK=32, ring-4 LDS, counted vmcnt, setprio ---------
__global__ __launch_bounds__(GTHREADS, 1) void gemm256(
    const unsigned short* __restrict__ A, const unsigned short* __restrict__ B,
    const float* __restrict__ bias, float* __restrict__ out) {
  extern __shared__ char smem[];

  const int t = threadIdx.x;
  const int lane = t & 63, wid = t >> 6;
  const int wr = wid >> 2;          // 0..1 (M half)
  const int wc = wid & 3;           // 0..3 (N quarter)
  const int ln = lane & 15;
  const int kc = lane >> 4;         // 0..3 k-chunk of 8 bf16

  // T1: XCD swizzle (512 blocks, 8 XCDs; chunk = 4 bm x 16 bn per XCD,
  // concurrent 32 blocks form a 4x8 (bm,bn) rectangle)
  const int bid = blockIdx.x;
  const int bmi = (bid & 7) * 4 + ((bid >> 3) & 3);  // 0..31
  const int bni = bid >> 5;                          // 0..15
  const int bm0 = bmi * BM, bn0 = bni * BN;

  // staging: thread t owns 16B chunk c=t (rows 0-127) and c=512+t (rows 128-255)
  // chunk c: row=c>>2, stored col=c&3 holds data k-chunk (c&3)^((c>>3)&3)
  const int row_s = t >> 2;                   // 0..127
  const int kcd = (t & 3) ^ ((t >> 3) & 3);   // pre-swizzled global k-chunk
  const unsigned short* gA = A + (size_t)(bm0 + row_s) * K_TOT + kcd * 8;
  const unsigned short* gB = B + (size_t)(bn0 + row_s) * K_TOT + kcd * 8;
  char* ldsA = smem + t * 16;           // linear dest (global_load_lds rule)
  char* ldsB = smem + 16384 + t * 16;

  // ds_read side: same involution. (row>>1)&3 == (ln>>1)&3 (m*16, wr*128 = 0 mod 8)
  const int swz = (kc ^ ((ln >> 1) & 3)) * 16;
  const int base_a = (wr * 128 + ln) * 64 + swz;
  const int base_b = 16384 + (wc * 64 + ln) * 64 + swz;

  f32x4 acc[8][4];
#pragma unroll
  for (int i = 0; i < 8; ++i)
#pragma unroll
    for (int j = 0; j < 4; ++j) acc[i][j] = f32x4{0.f, 0.f, 0.f, 0.f};

#define STAGE_A(kt, bufi) do {                                        \
    const unsigned short* s_ = gA + (size_t)(kt) * BK;                \
    glds16(s_, ldsA + (bufi) * BUF_BYTES);                            \
    glds16(s_ + (size_t)128 * K_TOT, ldsA + (bufi) * BUF_BYTES + 8192); \
  } while (0)
#define STAGE_B(kt, bufi) do {                                        \
    const unsigned short* s_ = gB + (size_t)(kt) * BK;                \
    glds16(s_, ldsB + (bufi) * BUF_BYTES);                            \
    glds16(s_ + (size_t)128 * K_TOT, ldsB + (bufi) * BUF_BYTES + 8192); \
  } while (0)

  bf16x8 af[4], bf[4];

#define LOAD_A4(bufi, mb) do {                                        \
    const char* pa_ = smem + (bufi) * BUF_BYTES + base_a + (mb) * 1024; \
    af[0] = *(const bf16x8*)(pa_);                                    \
    af[1] = *(const bf16x8*)(pa_ + 1024);                             \
    af[2] = *(const bf16x8*)(pa_ + 2048);                             \
    af[3] = *(const bf16x8*)(pa_ + 3072);                             \
  } while (0)
#define LOAD_B4(bufi) do {                                            \
    const char* pb_ = smem + (bufi) * BUF_BYTES + base_b;             \
    bf[0] = *(const bf16x8*)(pb_);                                    \
    bf[1] = *(const bf16x8*)(pb_ + 1024);                             \
    bf[2] = *(const bf16x8*)(pb_ + 2048);                             \
    bf[3] = *(const bf16x8*)(pb_ + 3072);                             \
  } while (0)

#define MFMA16(mb) do {                                               \
    __builtin_amdgcn_s_setprio(1);                                    \
    _Pragma("unroll")                                                 \
    for (int m_ = 0; m_ < 4; ++m_)                                    \
      _Pragma("unroll")                                               \
      for (int n_ = 0; n_ < 4; ++n_)                                  \
        acc[(mb) + m_][n_] = __builtin_amdgcn_mfma_f32_16x16x32_bf16( \
            af[m_], bf[n_], acc[(mb) + m_][n_], 0, 0, 0);             \
    __builtin_amdgcn_s_setprio(0);                                    \
  } while (0)

  // ---- prologue: stage tiles 0,1,2 (issue order fenced for vmcnt accounting)
  STAGE_A(0, 0); STAGE_B(0, 0);
  asm volatile("" ::: "memory");
  STAGE_A(1, 1); STAGE_B(1, 1);
  asm volatile("" ::: "memory");
  STAGE_A(2, 2); STAGE_B(2, 2);
  asm volatile("s_waitcnt vmcnt(8)" ::: "memory");  // tile 0 landed
  __builtin_amdgcn_s_barrier();

  // ---- main loop: compute tile tt from buf[tt&3], stage tile tt+3
  for (int tt = 0; tt < NT - 3; ++tt) {
    const int cb = tt & 3, sb = (tt + 3) & 3;
    // phase A: B frags + A m0-3; stage A half-tiles of tt+3
    LOAD_A4(cb, 0);
    LOAD_B4(cb);
    STAGE_A(tt + 3, sb);
    __builtin_amdgcn_s_barrier();
    MFMA16(0);
    __builtin_amdgcn_s_barrier();
    // phase B: A m4-7; stage B half-tiles of tt+3
    LOAD_A4(cb, 4);
    STAGE_B(tt + 3, sb);
    __builtin_amdgcn_s_barrier();
    MFMA16(4);
    // tiles tt+2, tt+3 (8 loads) may stay in flight; tt+1 landed after this
    asm volatile("s_waitcnt vmcnt(8)" ::: "memory");
    __builtin_amdgcn_s_barrier();
  }

  // ---- tail: tiles NT-3..NT-1, no staging, drain 4 -> 0
  for (int tt = NT - 3; tt < NT; ++tt) {
    const int cb = tt & 3;
    LOAD_A4(cb, 0);
    LOAD_B4(cb);
    __builtin_amdgcn_s_barrier();
    MFMA16(0);
    __builtin_amdgcn_s_barrier();
    LOAD_A4(cb, 4);
    __builtin_amdgcn_s_barrier();
    MFMA16(4);
    if (tt == NT - 3) asm volatile("s_waitcnt vmcnt(4)" ::: "memory");
    else if (tt == NT - 2) asm volatile("s_waitcnt vmcnt(0)" ::: "memory");
    __builtin_amdgcn_s_barrier();
  }

  // ---- epilogue: C/D layout col = lane&15, row = (lane>>4)*4 + q
  const int orow0 = bm0 + wr * 128 + (lane >> 4) * 4;
  const int ocol0 = bn0 + wc * 64 + ln;
  float bj[4];
#pragma unroll
  for (int n = 0; n < 4; ++n) bj[n] = bias[ocol0 + n * 16];
#pragma unroll
  for (int mi = 0; mi < 8; ++mi)
#pragma unroll
    for (int n = 0; n < 4; ++n)
#pragma unroll
      for (int q = 0; q < 4; ++q)
        out[(size_t)(orow0 + mi * 16 + q) * N_TOT + ocol0 + n * 16] =
            acc[mi][n][q] + bj[n];
}

extern "C" void kernel_launch(void* const* d_in, const int* in_sizes, int n_in,
                              void* d_out, int out_size, void* d_ws, size_t ws_size,
                              hipStream_t stream) {
  const float* x = (const float*)d_in[0];
  const int* widx = (const int*)d_in[1];
  const float* wsc = (const float*)d_in[2];
  const float* bias = (const float*)d_in[3];
  float* out = (float*)d_out;

  unsigned short* Abf = (unsigned short*)d_ws;                       // 64 MiB
  unsigned short* Wbf = (unsigned short*)((char*)d_ws + (size_t)M_TOT * K_TOT * 2);  // 32 MiB

  convert_x_kernel<<<dim3((M_TOT * (size_t)K_TOT / 8) / 256), dim3(256), 0, stream>>>(x, Abf);
  dequant_w_kernel<<<dim3((N_TOT * (size_t)K_TOT / 4) / 256), dim3(256), 0, stream>>>(widx, wsc, Wbf);

  (void)hipFuncSetAttribute((const void*)gemm256,
                            hipFuncAttributeMaxDynamicSharedMemorySize, LDS_BYTES);
  gemm256<<<dim3((M_TOT / BM) * (N_TOT / BN)), dim3(GTHREADS), LDS_BYTES, stream>>>(
      Abf, Wbf, bias, out);
}

// Round 3
// 279.221 us; speedup vs baseline: 1.3367x; 1.0483x over previous
//
#include <hip/hip_runtime.h>
#include <hip/hip_bf16.h>

static constexpr int M_TOT = 8192;   // 4 * 2048
static constexpr int N_TOT = 4096;   // OUT_F
static constexpr int K_TOT = 4096;   // IN_F

static constexpr int BM = 256, BN = 256, BK = 32;
static constexpr int NT = K_TOT / BK;        // 128 K-tiles
static constexpr int GTHREADS = 512;         // 8 waves (2 M x 4 N)
static constexpr int BUF_BYTES = 32768;      // A 16K + B 16K per K-tile buffer
static constexpr int LDS_BYTES = 4 * BUF_BYTES;  // ring-4 = 128 KiB

typedef __bf16 bf16x8 __attribute__((ext_vector_type(8)));
typedef float f32x4 __attribute__((ext_vector_type(4)));
typedef unsigned short u16x8 __attribute__((ext_vector_type(8)));

__device__ __forceinline__ unsigned short f2bf(float f) {
  return __builtin_bit_cast(unsigned short, (__bf16)f);
}

// FP4 E2M1 decode: mag 0..7 -> 0,0.5,1,1.5,2,3,4,6 ; bit 3 = sign
__device__ __forceinline__ float fp4_decode(int idx) {
  unsigned u = (unsigned)idx & 15u;
  unsigned sgn = (u >> 3) << 31;
  unsigned mag = u & 7u;
  unsigned e = mag >> 1, m = mag & 1u;
  unsigned bits = (e == 0u) ? (m ? 0x3F000000u : 0u)
                            : (((126u + e) << 23) | (m << 22));
  return __uint_as_float(bits | sgn);
}

__device__ __forceinline__ void glds16(const void* g, void* l) {
  __builtin_amdgcn_global_load_lds(
      (__attribute__((address_space(1))) void*)g,
      (__attribute__((address_space(3))) void*)l, 16, 0, 0);
}

// ---- prepass: weights int32 idx + scales -> bf16 W [N][K] -------------------
__global__ __launch_bounds__(256) void dequant_w_kernel(
    const int* __restrict__ idx, const float* __restrict__ scales,
    unsigned short* __restrict__ W) {
  const int t = blockIdx.x * 256 + threadIdx.x;  // 4 indices per thread
  const int4 v = reinterpret_cast<const int4*>(idx)[t];
  const float s = scales[t >> 2];
  ushort4 o;
  o.x = f2bf(fp4_decode(v.x) * s);
  o.y = f2bf(fp4_decode(v.y) * s);
  o.z = f2bf(fp4_decode(v.z) * s);
  o.w = f2bf(fp4_decode(v.w) * s);
  reinterpret_cast<ushort4*>(W)[t] = o;
}

// ---- prepass: x fp32 -> bf16 A [M][K] ---------------------------------------
__global__ __launch_bounds__(256) void convert_x_kernel(
    const float* __restrict__ x, unsigned short* __restrict__ A) {
  const int t = blockIdx.x * 256 + threadIdx.x;  // 8 floats per thread
  const float4* xp = reinterpret_cast<const float4*>(x);
  const float4 a = xp[2 * t], b = xp[2 * t + 1];
  u16x8 o;
  o[0] = f2bf(a.x); o[1] = f2bf(a.y); o[2] = f2bf(a.z); o[3] = f2bf(a.w);
  o[4] = f2bf(b.x); o[5] = f2bf(b.y); o[6] = f2bf(b.z); o[7] = f2bf(b.w);
  reinterpret_cast<u16x8*>(A)[t] = o;
}

// ---- GEMM: 256x256 tile, BK=32, ring-4 LDS, reg-dbuf frags, counted vmcnt ---
__global__ __launch_bounds__(GTHREADS, 1) void gemm256(
    const unsigned short* __restrict__ A, const unsigned short* __restrict__ B,
    const float* __restrict__ bias, float* __restrict__ out) {
  extern __shared__ char smem[];

  const int t = threadIdx.x;
  const int lane = t & 63, wid = t >> 6;
  const int wr = wid >> 2;          // 0..1 (M half)
  const int wc = wid & 3;           // 0..3 (N quarter)
  const int ln = lane & 15;
  const int kc = lane >> 4;         // 0..3 k-chunk of 8 bf16

  // T1: XCD swizzle (512 blocks, 8 XCDs)
  const int bid = blockIdx.x;
  const int bmi = (bid & 7) * 4 + ((bid >> 3) & 3);  // 0..31
  const int bni = bid >> 5;                          // 0..15
  const int bm0 = bmi * BM, bn0 = bni * BN;

  // staging: thread t writes 16B chunk at linear LDS pos; source k-chunk
  // pre-swizzled (involution c' = c ^ ((row>>1)&3), rows are 64B)
  const int row_s = t >> 2;                   // 0..127
  const int kcd = (t & 3) ^ ((t >> 3) & 3);   // pre-swizzled global k-chunk
  const unsigned short* gA = A + (size_t)(bm0 + row_s) * K_TOT + kcd * 8;
  const unsigned short* gB = B + (size_t)(bn0 + row_s) * K_TOT + kcd * 8;
  char* ldsA = smem + t * 16;
  char* ldsB = smem + 16384 + t * 16;

  // ds_read side: same involution ((row>>1)&3 == (ln>>1)&3 since frag rows
  // differ by multiples of 16)
  const int swz = (kc ^ ((ln >> 1) & 3)) * 16;
  const int base_a = (wr * 128 + ln) * 64 + swz;
  const int base_b = 16384 + (wc * 64 + ln) * 64 + swz;

  f32x4 acc[8][4];
#pragma unroll
  for (int i = 0; i < 8; ++i)
#pragma unroll
    for (int j = 0; j < 4; ++j) acc[i][j] = f32x4{0.f, 0.f, 0.f, 0.f};

  bf16x8 afA[4], afB[4], bfE[4], bfO[4];

#define STAGE_A(kt, bufi) do {                                          \
    const unsigned short* s_ = gA + (size_t)(kt) * BK;                  \
    glds16(s_, ldsA + (bufi) * BUF_BYTES);                              \
    glds16(s_ + (size_t)128 * K_TOT, ldsA + (bufi) * BUF_BYTES + 8192); \
  } while (0)
#define STAGE_B(kt, bufi) do {                                          \
    const unsigned short* s_ = gB + (size_t)(kt) * BK;                  \
    glds16(s_, ldsB + (bufi) * BUF_BYTES);                              \
    glds16(s_ + (size_t)128 * K_TOT, ldsB + (bufi) * BUF_BYTES + 8192); \
  } while (0)

#define READ_AF(dst, bufi, mb) do {                                     \
    const char* p_ = smem + (bufi) * BUF_BYTES + base_a + (mb) * 1024;  \
    dst[0] = *(const bf16x8*)(p_);                                      \
    dst[1] = *(const bf16x8*)(p_ + 1024);                               \
    dst[2] = *(const bf16x8*)(p_ + 2048);                               \
    dst[3] = *(const bf16x8*)(p_ + 3072);                               \
  } while (0)
#define READ_BF(dst, bufi) do {                                         \
    const char* p_ = smem + (bufi) * BUF_BYTES + base_b;                \
    dst[0] = *(const bf16x8*)(p_);                                      \
    dst[1] = *(const bf16x8*)(p_ + 1024);                               \
    dst[2] = *(const bf16x8*)(p_ + 2048);                               \
    dst[3] = *(const bf16x8*)(p_ + 3072);                               \
  } while (0)

#define MFMA16(afs, bfs, mb) do {                                       \
    __builtin_amdgcn_s_setprio(1);                                      \
    _Pragma("unroll")                                                   \
    for (int m_ = 0; m_ < 4; ++m_)                                      \
      _Pragma("unroll")                                                 \
      for (int n_ = 0; n_ < 4; ++n_)                                    \
        acc[(mb) + m_][n_] = __builtin_amdgcn_mfma_f32_16x16x32_bf16(   \
            afs[m_], bfs[n_], acc[(mb) + m_][n_], 0, 0, 0);             \
    __builtin_amdgcn_s_setprio(0);                                      \
  } while (0)

#define VM(n) asm volatile("s_waitcnt vmcnt(" #n ")" ::: "memory")
#define BAR __builtin_amdgcn_s_barrier()

  // Phase A of tile tt (data in buf rb): read af m4-7 of tt, stage A(tt+3),
  // MFMA rows 0-3, then vmcnt(6) + barrier => tile tt+1 landed GLOBALLY.
#define PH_A(tt, rb, sb, bfc) do { \
    READ_AF(afB, rb, 4);           \
    STAGE_A((tt) + 3, sb);         \
    MFMA16(afA, bfc, 0);           \
    VM(6); BAR;                    \
  } while (0)
  // Phase B of tile tt: read-ahead af m0-3 + bf of tile tt+1 (safe: landed),
  // stage B(tt+3), MFMA rows 4-7, barrier.
#define PH_B(tt, rbn, sb, bfc, bfn) do { \
    READ_AF(afA, rbn, 0);                \
    READ_BF(bfn, rbn);                   \
    STAGE_B((tt) + 3, sb);               \
    MFMA16(afB, bfc, 4);                 \
    BAR;                                 \
  } while (0)

  // ---- prologue: stage tiles 0,1,2 (order pinned for vmcnt accounting)
  STAGE_A(0, 0); STAGE_B(0, 0);
  asm volatile("" ::: "memory");
  STAGE_A(1, 1); STAGE_B(1, 1);
  asm volatile("" ::: "memory");
  STAGE_A(2, 2); STAGE_B(2, 2);
  VM(8);  // tile 0 landed (own); barrier makes it global
  BAR;
  READ_AF(afA, 0, 0);
  READ_BF(bfE, 0);

  // ---- main loop: tiles 0..123, stages 3..126 (4-tile unroll, static bufs)
#pragma unroll 1
  for (int tt = 0; tt < NT - 4; tt += 4) {
    PH_A(tt + 0, 0, 3, bfE);
    PH_B(tt + 0, 1, 3, bfE, bfO);
    PH_A(tt + 1, 1, 0, bfO);
    PH_B(tt + 1, 2, 0, bfO, bfE);
    PH_A(tt + 2, 2, 1, bfE);
    PH_B(tt + 2, 3, 1, bfE, bfO);
    PH_A(tt + 3, 3, 2, bfO);
    PH_B(tt + 3, 0, 2, bfO, bfE);
  }

  // ---- tail: tiles 124..127, drain 6 -> 4 -> 0
  // tile 124 (buf0), stages tile 127 -> buf3
  READ_AF(afB, 0, 4); STAGE_A(127, 3); MFMA16(afA, bfE, 0); VM(6); BAR;
  READ_AF(afA, 1, 0); READ_BF(bfO, 1); STAGE_B(127, 3); MFMA16(afB, bfE, 4); BAR;
  // tile 125 (buf1): newest allowed = A(127)+B(127) = 4 => tile 126 landed
  READ_AF(afB, 1, 4); MFMA16(afA, bfO, 0); VM(4); BAR;
  READ_AF(afA, 2, 0); READ_BF(bfE, 2); MFMA16(afB, bfO, 4); BAR;
  // tile 126 (buf2): drain all => tile 127 landed
  READ_AF(afB, 2, 4); MFMA16(afA, bfE, 0); VM(0); BAR;
  READ_AF(afA, 3, 0); READ_BF(bfO, 3); MFMA16(afB, bfE, 4); BAR;
  // tile 127 (buf3)
  READ_AF(afB, 3, 4); MFMA16(afA, bfO, 0);
  MFMA16(afB, bfO, 4);

  // ---- epilogue: C/D layout col = lane&15, row = (lane>>4)*4 + q
  const int orow0 = bm0 + wr * 128 + (lane >> 4) * 4;
  const int ocol0 = bn0 + wc * 64 + ln;
  float bj[4];
#pragma unroll
  for (int n = 0; n < 4; ++n) bj[n] = bias[ocol0 + n * 16];
#pragma unroll
  for (int mi = 0; mi < 8; ++mi)
#pragma unroll
    for (int n = 0; n < 4; ++n)
#pragma unroll
      for (int q = 0; q < 4; ++q)
        out[(size_t)(orow0 + mi * 16 + q) * N_TOT + ocol0 + n * 16] =
            acc[mi][n][q] + bj[n];
}

extern "C" void kernel_launch(void* const* d_in, const int* in_sizes, int n_in,
                              void* d_out, int out_size, void* d_ws, size_t ws_size,
                              hipStream_t stream) {
  const float* x = (const float*)d_in[0];
  const int* widx = (const int*)d_in[1];
  const float* wsc = (const float*)d_in[2];
  const float* bias = (const float*)d_in[3];
  float* out = (float*)d_out;

  unsigned short* Abf = (unsigned short*)d_ws;                       // 64 MiB
  unsigned short* Wbf = (unsigned short*)((char*)d_ws + (size_t)M_TOT * K_TOT * 2);  // 32 MiB

  convert_x_kernel<<<dim3((M_TOT * (size_t)K_TOT / 8) / 256), dim3(256), 0, stream>>>(x, Abf);
  dequant_w_kernel<<<dim3((N_TOT * (size_t)K_TOT / 4) / 256), dim3(256), 0, stream>>>(widx, wsc, Wbf);

  (void)hipFuncSetAttribute((const void*)gemm256,
                            hipFuncAttributeMaxDynamicSharedMemorySize, LDS_BYTES);
  gemm256<<<dim3((M_TOT / BM) * (N_TOT / BN)), dim3(GTHREADS), LDS_BYTES, stream>>>(
      Abf, Wbf, bias, out);
}